// Round 1
// baseline (103.546 us; speedup 1.0000x reference)
//
#include <hip/hip_runtime.h>
#include <math.h>

// Problem constants (from reference)
#define BS        1048576
#define N_AGENTS  8
#define N_HEAD    4
#define EMBED_DIM 64

// Output layout (flat f32, concatenated in return order):
//   [0,            BS*8)      head_attend  == 0.5f everywhere (uniform softmax over
//                                             identical logits, summed over 4 heads)
//   [BS*8,         BS*9)      v            == V[0] broadcast
//   [BS*9]                    attend_mag_regs = 0.001 * sum_h dot(sel_w[h],key_w[h])^2
//   [BS*9+1, BS*9+5)          head_entropies  = -log(0.125+1e-8) per head (constant)
//
// Total = 9437189 floats. First 9437184 are float4-aligned fill regions.

__global__ __launch_bounds__(256) void qatten_kernel(
    const float* __restrict__ sel_w,   // (4,64) flat = 256
    const float* __restrict__ key_w,   // (4,64) flat = 256
    const float* __restrict__ Vp,      // (1,)
    float* __restrict__ out)
{
    const int NF4_HEAD = (BS * N_AGENTS) / 4;        // 2097152 float4s of 0.5
    const int NF4_TOT  = (BS * (N_AGENTS + 1)) / 4;  // 2359296 float4s total fill

    int i = blockIdx.x * blockDim.x + threadIdx.x;
    if (i < NF4_TOT) {
        float val = (i < NF4_HEAD) ? 0.5f : Vp[0];
        reinterpret_cast<float4*>(out)[i] = make_float4(val, val, val, val);
    }

    // Block 0 additionally computes the two scalar tail outputs.
    if (blockIdx.x == 0) {
        const int t = threadIdx.x;                 // 256 threads == 4 waves of 64
        float prod = sel_w[t] * key_w[t];          // one product per (head, dim)
        // wave-64 butterfly: head h == wave h (lanes 64h..64h+63)
        #pragma unroll
        for (int off = 32; off > 0; off >>= 1)
            prod += __shfl_down(prod, off, 64);

        __shared__ float dots[N_HEAD];
        const int lane = t & 63;
        const int wave = t >> 6;
        if (lane == 0) dots[wave] = prod;          // dot(sel_w[h], key_w[h])
        __syncthreads();

        if (t == 0) {
            float s = 0.0f;
            #pragma unroll
            for (int h = 0; h < N_HEAD; ++h) s += dots[h] * dots[h];
            out[(long long)BS * 9] = 0.001f * s;
        }
        if (t < N_HEAD) {
            // probs are exactly 1/8; entropy = -sum_a p*log(p+1e-8) = -log(0.125+1e-8)
            const float p = 0.125f;
            out[(long long)BS * 9 + 1 + t] = -(8.0f * (p * logf(p + 1e-8f)));
        }
    }
}

extern "C" void kernel_launch(void* const* d_in, const int* in_sizes, int n_in,
                              void* d_out, int out_size, void* d_ws, size_t ws_size,
                              hipStream_t stream) {
    // inputs: 0=agent_qs (unused), 1=actions (unused), 2=sel_w, 3=key_w, 4=V
    const float* sel_w = (const float*)d_in[2];
    const float* key_w = (const float*)d_in[3];
    const float* Vp    = (const float*)d_in[4];
    float* out = (float*)d_out;

    const int NF4_TOT = (BS * (N_AGENTS + 1)) / 4;   // 2359296
    const int block = 256;
    const int grid  = (NF4_TOT + block - 1) / block; // 9216 blocks
    qatten_kernel<<<grid, block, 0, stream>>>(sel_w, key_w, Vp, out);
}